// Round 14
// baseline (8199.730 us; speedup 1.0000x reference)
//
#include <hip/hip_runtime.h>
#include <hip/hip_bf16.h>
#include <math.h>

typedef __bf16 bf16x8 __attribute__((ext_vector_type(8)));
typedef float f32x4 __attribute__((ext_vector_type(4)));
typedef unsigned long long u64;
typedef u64 u64x2 __attribute__((ext_vector_type(2)));

#define TT 512
#define ISZ 1024
#define HSZ 4096
#define NBLK 256
#define NTHR 512
#define LN_EPS 1e-6f
#define SCOPE_AGENT __HIP_MEMORY_SCOPE_AGENT

union U128 { u64 u[2]; u64x2 p; bf16x8 v; };

// consumer of remote-written data: non-temporal load (no allocate -> no staleness)
__device__ __forceinline__ bf16x8 nt_ld16(const __bf16* p) {
  U128 r;
  r.p = __builtin_nontemporal_load((const u64x2*)p);
  return r.v;
}
// producer to cross-XCD master buffers: relaxed agent write-through (validated R3-R13)
__device__ __forceinline__ void coh_st16(__bf16* p, bf16x8 v) {
  U128 r; r.v = v;
  u64* q = (u64*)p;
  __hip_atomic_store(q,     r.u[0], __ATOMIC_RELAXED, SCOPE_AGENT);
  __hip_atomic_store(q + 1, r.u[1], __ATOMIC_RELAXED, SCOPE_AGENT);
}

// exact-grade GELU: Abramowitz-Stegun 7.1.26 erf (|eps|<=1.5e-7), branchless
__device__ __forceinline__ float gelu_f(float v) {
  const float u = v * 0.70710678118654752f;
  const float x = fabsf(u);
  const float t = __builtin_amdgcn_rcpf(fmaf(0.3275911f, x, 1.0f));
  float p = fmaf(1.061405429f, t, -1.453152027f);
  p = fmaf(p, t, 1.421413741f);
  p = fmaf(p, t, -0.284496736f);
  p = fmaf(p, t, 0.254829592f);
  p = p * t;
  const float e = p * __expf(-x * x);
  const float erfv = copysignf(1.0f - e, u);
  return 0.5f * v * (1.0f + erfv);
}

// frag-image index shared by hbf / abf / ablocal: [s2 128][g 4][lane 64][kk 8]
__device__ __forceinline__ int frag_idx(int row, int u) {
  return (((u >> 2) * 4 + (row >> 4)) * 64 + (u & 3) * 16 + (row & 15)) * 8;
}

// ---------------- prep kernels ----------------
// w1p layout: [nblk 256][kgrp 256][col 16][kk 8] bf16  (64 KB per nblk = LDS image)
__global__ void prep_w1(const float* __restrict__ W1, __bf16* __restrict__ w1p) {
  int t = blockIdx.x * blockDim.x + threadIdx.x;   // 1048576 threads
  int k = t >> 9;
  int n8 = (t & 511) << 3;
  const float* src = W1 + (size_t)k * HSZ + n8;
  float4 f0 = *(const float4*)src;
  float4 f1 = *(const float4*)(src + 4);
  int kgrp = k >> 3, kk = k & 7;
  float vals[8] = {f0.x, f0.y, f0.z, f0.w, f1.x, f1.y, f1.z, f1.w};
#pragma unroll
  for (int i = 0; i < 8; ++i) {
    int n = n8 + i;
    int nb = n >> 4, col = n & 15;
    w1p[(size_t)nb * 32768 + kgrp * 128 + col * 8 + kk] = (__bf16)vals[i];
  }
}

// w2p layout: [cg 64][kgrp 512][col 16][kk 8] bf16
__global__ void prep_w2(const float* __restrict__ W2, __bf16* __restrict__ w2p) {
  int t = blockIdx.x * blockDim.x + threadIdx.x;   // 524288 threads
  int k = t >> 7;
  int n8 = (t & 127) << 3;
  const float* src = W2 + (size_t)k * ISZ + n8;
  float4 f0 = *(const float4*)src;
  float4 f1 = *(const float4*)(src + 4);
  int kgrp = k >> 3, kk = k & 7;
  float vals[8] = {f0.x, f0.y, f0.z, f0.w, f1.x, f1.y, f1.z, f1.w};
#pragma unroll
  for (int i = 0; i < 8; ++i) {
    int n = n8 + i;
    int cg = n >> 4, col = n & 15;
    w2p[(size_t)cg * 65536 + kgrp * 128 + col * 8 + kk] = (__bf16)vals[i];
  }
}

// xbf layout per t: [kh 32][m 4][lane 64][kk 8] bf16 (128 KB) — GEMM1 A-frag image
__global__ void prep_x(const float* __restrict__ x, __bf16* __restrict__ xbf) {
  int tid = blockIdx.x * blockDim.x + threadIdx.x;  // 4194304 threads
  int c8 = tid & 127;
  int t = (tid >> 7) & 511;
  int row = tid >> 16;
  const float* src = x + ((size_t)row * TT + t) * ISZ + c8 * 8;
  float4 f0 = *(const float4*)src;
  float4 f1 = *(const float4*)(src + 4);
  float vals[8] = {f0.x, f0.y, f0.z, f0.w, f1.x, f1.y, f1.z, f1.w};
  bf16x8 v;
#pragma unroll
  for (int i = 0; i < 8; ++i) v[i] = (__bf16)vals[i];
  int kh = c8 >> 2, lane = (c8 & 3) * 16 + (row & 15), m = row >> 4;
  *(bf16x8*)&xbf[(size_t)t * 65536 + (((kh * 4 + m) * 64 + lane) << 3)] = v;
}

// hxbf layout: [kh 32][m 4][lane 64][kk 8] bf16
__global__ void prep_state(const float* __restrict__ init_hx,
                           float* __restrict__ hxf32, __bf16* __restrict__ hxbf,
                           unsigned* __restrict__ syncbuf) {
  int t = blockIdx.x * blockDim.x + threadIdx.x;   // 65536 threads
  int row = t >> 10, c = t & 1023;
  float v = init_hx[c];
  hxf32[t] = v;
  int kh = c >> 5, l = ((c >> 3) & 3) * 16 + (row & 15), m = row >> 4;
  hxbf[((kh * 4 + m) * 64 + l) * 8 + (c & 7)] = (__bf16)v;
  if (t < 16672) syncbuf[t] = 0u;       // arr + gflag + xarr + tickets
}

// ---- fence-free 2-hop global barrier, split arrive/wait ----
__device__ __forceinline__ void gbar_arrive(unsigned* __restrict__ arr,
                                            int j, unsigned target) {
  __syncthreads();                       // drains each wave's own stores
  if (threadIdx.x == 0)
    __hip_atomic_store(&arr[j * 32], target, __ATOMIC_RELAXED, SCOPE_AGENT);
}
__device__ __forceinline__ void gbar_wait(unsigned* __restrict__ arr,
                                          unsigned* __restrict__ gflag,
                                          int j, unsigned target) {
  const int tid = threadIdx.x;
  if (j < 8 && tid < 32) {               // wave 0 of blocks 0..7: group aggregator
    const unsigned* p = &arr[(tid * 8 + j) * 32];
    int guard = 0;
    for (;;) {
      unsigned v = __hip_atomic_load(p, __ATOMIC_RELAXED, SCOPE_AGENT);
      if (__all(v >= target)) break;
      if (++guard > (1 << 20)) break;    // fail-safe: wrong answer beats a hang
      __builtin_amdgcn_s_sleep(1);
    }
    asm volatile("" ::: "memory");
    if (tid == 0)
      __hip_atomic_store(&gflag[j * 32], target, __ATOMIC_RELAXED, SCOPE_AGENT);
  }
  if (tid < 8) {                         // everyone: poll the 8 group flags
    const unsigned* p = &gflag[tid * 32];
    int guard = 0;
    for (;;) {
      unsigned v = __hip_atomic_load(p, __ATOMIC_RELAXED, SCOPE_AGENT);
      if (__all(v >= target)) break;
      if (++guard > (1 << 20)) break;
      __builtin_amdgcn_s_sleep(1);
    }
  }
  asm volatile("" ::: "memory");
  __syncthreads();
}
__device__ __forceinline__ void gbar(unsigned* __restrict__ arr,
                                     unsigned* __restrict__ gflag,
                                     int j, unsigned target) {
  gbar_arrive(arr, j, target);
  gbar_wait(arr, gflag, j, target);
}

// ---- XCD-local 1-hop barrier, split arrive/wait ----
__device__ __forceinline__ void xbar_arrive(unsigned* __restrict__ xarr,
                                            int xk, int xrank, unsigned target) {
  __syncthreads();
  if (threadIdx.x == 0)
    __hip_atomic_store(&xarr[(xk * 32 + xrank) * 32], target, __ATOMIC_RELAXED, SCOPE_AGENT);
}
__device__ __forceinline__ void xbar_wait(unsigned* __restrict__ xarr,
                                          int xk, unsigned target) {
  const int tid = threadIdx.x;
  if (tid < 32) {
    const unsigned* p = &xarr[(xk * 32 + tid) * 32];
    int guard = 0;
    for (;;) {
      unsigned v = __hip_atomic_load(p, __ATOMIC_RELAXED, SCOPE_AGENT);
      if (__all(v >= target)) break;
      if (++guard > (1 << 20)) break;
      __builtin_amdgcn_s_sleep(1);
    }
  }
  asm volatile("" ::: "memory");
  __syncthreads();
}

// ---------------- persistent RNN kernel ----------------
template <bool USE_XBF>
__global__ __launch_bounds__(NTHR, 1) void rnn_persist(
    const float* __restrict__ x, const float* __restrict__ b1,
    const float* __restrict__ ln_g, const float* __restrict__ ln_b,
    const float* __restrict__ b2, float* __restrict__ out,
    const __bf16* __restrict__ w1p, const __bf16* __restrict__ w2p,
    const __bf16* __restrict__ xbf,
    __bf16* __restrict__ hbf, __bf16* __restrict__ abf,
    __bf16* __restrict__ ablocal, __bf16* __restrict__ hxlocal,
    __bf16* __restrict__ hxbf,
    float* __restrict__ hxf32, unsigned* __restrict__ arr,
    unsigned* __restrict__ gflag, unsigned* __restrict__ xarr,
    unsigned* __restrict__ ticket)
{
  __shared__ __bf16 w1s[32768];   // 64 KB [kgrp 256][col 16][kk 8]
  __shared__ float red[8192];     // 32 KB cross-wave reduction + stat partials
  __shared__ __bf16 abuf[1024];   // 2 KB h-tile repack / hx-tile pack
  __shared__ int sh_meta[4];      // xk, xrank, lmode

  const int j = blockIdx.x;
  const int tid = threadIdx.x;
  const int w = tid >> 6;
  const int l = tid & 63;
  const int l4 = l >> 4, l15 = l & 15;

  // physical-XCD ticket (once per kernel)
  if (tid == 0) {
    unsigned xcd = ((unsigned)__builtin_amdgcn_s_getreg(63508)) & 7u;  // HW_REG_XCC_ID
    unsigned r = __hip_atomic_fetch_add(&ticket[xcd], 1u, __ATOMIC_RELAXED, SCOPE_AGENT);
    sh_meta[0] = (int)xcd;
    sh_meta[1] = (int)r;
  }

  { // stage this block's W1 slice into LDS (one-time)
    const bf16x8* src = (const bf16x8*)(w1p + (size_t)j * 32768);
    bf16x8* dst = (bf16x8*)w1s;
#pragma unroll
    for (int i = 0; i < 8; ++i) dst[tid + i * 512] = src[tid + i * 512];
  }

  unsigned tc = 1;
  gbar(arr, gflag, j, tc);               // all tickets taken, W1 staged; arr=1 everywhere

  if (tid == 0) {
    int ok = 1;
#pragma unroll
    for (int i = 0; i < 8; ++i)
      ok &= (__hip_atomic_load(&ticket[i], __ATOMIC_RELAXED, SCOPE_AGENT) == 32u);
    sh_meta[2] = ok && (sh_meta[1] < 32);
  }
  __syncthreads();
  const int xk = sh_meta[0];
  const int xrank = sh_meta[1];
  const bool lmode = (sh_meta[2] != 0);
  __bf16* abl = ablocal + (size_t)xk * 262144;   // this XCD's 512 KB abf copy
  __bf16* hxl = hxlocal + (size_t)xk * 65536;    // this XCD's 128 KB hx copy

  const float b1v = b1[j * 16 + l15];
  const int g = j >> 6, cg = j & 63;     // phase-C tile: rows 16g.., cols 16cg..
  const float b2v = b2[cg * 16 + l15];

  // fallback path: this wave's 32 hx-producer blocks
  const int prodj = ((l >> 3) & 3) * 64 + w * 8 + (l & 7);
  // lmode: the 8 producers of our staging slice (kh = xrank, cols xrank*32..+32):
  //   c in [xrank*32, xrank*32+32) -> cg in {2*xrank, 2*xrank+1}, g = 0..3
  const int stgj = ((tid >> 1) & 3) * 64 + 2 * xrank + (tid & 1);  // valid for tid<8

  // x-half of phase A for step tt, K-slices [i0,i1) of this wave's 4; i0==0 zero-inits
  auto do_xhalf_range = [&](int tt, f32x4* hac, int i0, int i1) {
    if (i0 == 0) {
#pragma unroll
      for (int m = 0; m < 4; ++m) hac[m] = (f32x4){0.f, 0.f, 0.f, 0.f};
    }
    for (int i = i0; i < i1; ++i) {      // ks = w*4+i  (0..31 over 8 waves)
      const int ks = w * 4 + i;
      bf16x8 bfr = *(const bf16x8*)&w1s[((4 * ks + l4) * 16 + l15) * 8];
      if (USE_XBF) {
        const __bf16* xb = xbf + (size_t)tt * 65536 + (size_t)ks * 2048;
#pragma unroll
        for (int m = 0; m < 4; ++m) {
          bf16x8 af = *(const bf16x8*)&xb[(m * 64 + l) * 8];
          hac[m] = __builtin_amdgcn_mfma_f32_16x16x32_bf16(af, bfr, hac[m], 0, 0, 0);
        }
      } else {
        const int k = ks * 32 + l4 * 8;
#pragma unroll
        for (int m = 0; m < 4; ++m) {
          const int row = m * 16 + l15;
          const float* p = x + ((size_t)row * TT + tt) * ISZ + k;
          float4 f0 = *(const float4*)p;
          float4 f1 = *(const float4*)(p + 4);
          bf16x8 af;
          af[0] = (__bf16)f0.x; af[1] = (__bf16)f0.y;
          af[2] = (__bf16)f0.z; af[3] = (__bf16)f0.w;
          af[4] = (__bf16)f1.x; af[5] = (__bf16)f1.y;
          af[6] = (__bf16)f1.z; af[7] = (__bf16)f1.w;
          hac[m] = __builtin_amdgcn_mfma_f32_16x16x32_bf16(af, bfr, hac[m], 0, 0, 0);
        }
      }
    }
  };

  for (int t = 0; t < TT; ++t) {
    f32x4 hac[4];
    if (lmode) {
      // ---------- x-half part 1 (2 K-slices): covers the stage-poll wait ----------
      do_xhalf_range(t, hac, 0, 2);
      // ---------- stage hx slice kh=xrank into XCD-local copy ----------
      if (tid < 8) {                     // poll our slice's 8 producers (post-C(t-1))
        const unsigned* p = &arr[stgj * 32];
        int guard = 0;
        for (;;) {
          unsigned v = __hip_atomic_load(p, __ATOMIC_RELAXED, SCOPE_AGENT);
          if (__all(v >= tc)) break;
          if (++guard > (1 << 20)) break;  // fail-safe
          __builtin_amdgcn_s_sleep(1);
        }
      }
      asm volatile("" ::: "memory");
      __syncthreads();                   // stage readers wait for the poll
      if (tid < 256) {                   // copy 4 KB slice: master(nt) -> local(cached)
        const int off = xrank * 2048 + tid * 8;
        bf16x8 v = nt_ld16(hxbf + off);
        *(bf16x8*)(hxl + off) = v;       // normal store: dirty line in OUR L2
      }
      ++tc; xbar_arrive(xarr, xk, xrank, tc);   // syncthreads drains the stores
      // ---------- x-half part 2 (2 K-slices): covers the xbar2 wait ----------
      do_xhalf_range(t, hac, 2, 4);
      xbar_wait(xarr, xk, tc);           // full hx staged in local L2

      // ---------- Phase A, hx-half: normal loads, local L2 hits ----------
#pragma unroll
      for (int i = 0; i < 4; ++i) {      // kh = w*4 .. w*4+4
        const int kh = w * 4 + i;
        bf16x8 bfr = *(const bf16x8*)&w1s[((4 * (32 + kh) + l4) * 16 + l15) * 8];
#pragma unroll
        for (int m = 0; m < 4; ++m) {
          bf16x8 af = *(const bf16x8*)&hxl[((kh * 4 + m) * 64 + l) * 8];
          hac[m] = __builtin_amdgcn_mfma_f32_16x16x32_bf16(af, bfr, hac[m], 0, 0, 0);
        }
      }
    } else {
      // ---------- fallback: R9 path (x-half, direct poll, nt hx reads) ----------
      do_xhalf_range(t, hac, 0, 4);
      {
        const unsigned* p = &arr[prodj * 32];
        int guard = 0;
        for (;;) {
          unsigned v = __hip_atomic_load(p, __ATOMIC_RELAXED, SCOPE_AGENT);
          if (__all(v >= tc)) break;
          if (++guard > (1 << 20)) break;
          __builtin_amdgcn_s_sleep(1);
        }
        asm volatile("" ::: "memory");
      }
      ++tc;                              // keep tc aligned with lmode's xbar2 bump
#pragma unroll
      for (int i = 0; i < 4; ++i) {
        const int kh = w * 4 + i;
        bf16x8 bfr = *(const bf16x8*)&w1s[((4 * (32 + kh) + l4) * 16 + l15) * 8];
#pragma unroll
        for (int m = 0; m < 4; ++m) {
          bf16x8 af = nt_ld16(&hxbf[((kh * 4 + m) * 64 + l) * 8]);
          hac[m] = __builtin_amdgcn_mfma_f32_16x16x32_bf16(af, bfr, hac[m], 0, 0, 0);
        }
      }
    }

#pragma unroll
    for (int m = 0; m < 4; ++m)
      *(f32x4*)&red[((w * 4 + m) * 64 + l) * 4] = hac[m];
    __syncthreads();
    if (w < 4) {                         // wave w owns m-tile w: rows 16w..16w+16
      f32x4 h = *(const f32x4*)&red[((0 * 4 + w) * 64 + l) * 4];
#pragma unroll
      for (int s = 1; s < 8; ++s)
        h += *(const f32x4*)&red[((s * 4 + w) * 64 + l) * 4];
#pragma unroll
      for (int r = 0; r < 4; ++r)        // C layout: col=l15, row=16w+4*l4+r
        abuf[(w * 16 + l4 * 4 + r) * 16 + l15] = (__bf16)(h[r] + b1v);
    }
    __syncthreads();
    if (tid < 128) {                     // h-tile -> hbf master frag image (coherent)
      const int m = tid >> 5, q2s = (tid >> 4) & 1, rr = tid & 15;
      bf16x8 vv = *(const bf16x8*)&abuf[(m * 16 + rr) * 16 + q2s * 8];
      const int k2 = j >> 1, q2 = (j & 1) * 2 + q2s;
      coh_st16(&hbf[(((k2 * 4 + m) * 64) + q2 * 16 + rr) * 8], vv);
    }
    ++tc; gbar(arr, gflag, j, tc);       // post-A: h globally visible

    // ---------- Phase B: a = gelu(LN(h)) computed once per XCD copy ----------
    if (lmode) {
      const int u = tid;
      const int R0 = xrank * 2, R1 = R0 + 1;
      const int i0 = frag_idx(R0, u), i1 = frag_idx(R1, u);
      bf16x8 h0 = nt_ld16(hbf + i0);
      bf16x8 h1 = nt_ld16(hbf + i1);
      float s0 = 0.f, q0 = 0.f, s1 = 0.f, q1 = 0.f;
#pragma unroll
      for (int e = 0; e < 8; ++e) {
        float v0 = (float)h0[e], v1 = (float)h1[e];
        s0 += v0; q0 += v0 * v0; s1 += v1; q1 += v1 * v1;
      }
#pragma unroll
      for (int m = 1; m < 64; m <<= 1) {
        s0 += __shfl_xor(s0, m, 64); q0 += __shfl_xor(q0, m, 64);
        s1 += __shfl_xor(s1, m, 64); q1 += __shfl_xor(q1, m, 64);
      }
      if (l == 0) *(f32x4*)&red[4096 + w * 4] = (f32x4){s0, q0, s1, q1};
      __syncthreads();
      float S0 = 0.f, Q0 = 0.f, S1 = 0.f, Q1 = 0.f;
#pragma unroll
      for (int w2 = 0; w2 < 8; ++w2) {
        f32x4 p = *(const f32x4*)&red[4096 + w2 * 4];
        S0 += p[0]; Q0 += p[1]; S1 += p[2]; Q1 += p[3];
      }
      const float mu0 = S0 * (1.f / 4096.f), mu1 = S1 * (1.f / 4096.f);
      const float rs0 = rsqrtf(Q0 * (1.f / 4096.f) - mu0 * mu0 + LN_EPS);
      const float rs1 = rsqrtf(Q1 * (1.f / 4096.f) - mu1 * mu1 + LN_EPS);
      const int c0 = (u >> 2) * 32 + (u & 3) * 8;
      float4 ga = *(const float4*)(ln_g + c0), gb = *(const float4*)(ln_g + c0 + 4);
      float4 ea = *(const float4*)(ln_b + c0), eb = *(const float4*)(ln_b + c0 + 4);
      float gk[8] = {ga.x, ga.y, ga.z, ga.w, gb.x, gb.y, gb.z, gb.w};
      float ek[8] = {ea.x, ea.y, ea.z, ea.w, eb.x, eb.y, eb.z, eb.w};
      bf16x8 a0, a1;
#pragma unroll
      for (int e = 0; e < 8; ++e) {
        a0[e] = (__bf16)gelu_f(((float)h0[e] - mu0) * rs0 * gk[e] + ek[e]);
        a1[e] = (__bf16)gelu_f(((float)h1[e] - mu1) * rs1 * gk[e] + ek[e]);
      }
      *(bf16x8*)(abl + i0) = a0;         // normal cached stores: XCD-local copy
      *(bf16x8*)(abl + i1) = a1;
    } else {                             // fallback: gelu once into master abf
      const int u = tid;
      const int R = j >> 2, q = j & 3;
      const int iR = frag_idx(R, u);
      bf16x8 hv = nt_ld16(hbf + iR);
      float s0 = 0.f, q0 = 0.f;
#pragma unroll
      for (int e = 0; e < 8; ++e) { float v = (float)hv[e]; s0 += v; q0 += v * v; }
#pragma unroll
      for (int m = 1; m < 64; m <<= 1) {
        s0 += __shfl_xor(s0, m, 64); q0 += __shfl_xor(q0, m, 64);
      }
      if (l == 0) { red[4096 + w * 2] = s0; red[4096 + w * 2 + 1] = q0; }
      __syncthreads();
      float S = 0.f, Q = 0.f;
#pragma unroll
      for (int w2 = 0; w2 < 8; ++w2) { S += red[4096 + w2 * 2]; Q += red[4096 + w2 * 2 + 1]; }
      const float mu = S * (1.f / 4096.f);
      const float rs = rsqrtf(Q * (1.f / 4096.f) - mu * mu + LN_EPS);
      if ((tid >> 7) == q) {
        const int c0 = (u >> 2) * 32 + (u & 3) * 8;
        float4 ga = *(const float4*)(ln_g + c0), gb = *(const float4*)(ln_g + c0 + 4);
        float4 ea = *(const float4*)(ln_b + c0), eb = *(const float4*)(ln_b + c0 + 4);
        float gk[8] = {ga.x, ga.y, ga.z, ga.w, gb.x, gb.y, gb.z, gb.w};
        float ek[8] = {ea.x, ea.y, ea.z, ea.w, eb.x, eb.y, eb.z, eb.w};
        bf16x8 av;
#pragma unroll
        for (int e = 0; e < 8; ++e)
          av[e] = (__bf16)gelu_f(((float)hv[e] - mu) * rs * gk[e] + ek[e]);
        coh_st16(abf + iR, av);
      }
    }

    // ---------- B->C sync with w2p prefetch hidden between arrive and wait ----------
    ++tc;
    if (lmode) xbar_arrive(xarr, xk, xrank, tc);
    else       gbar_arrive(arr, j, tc);
    bf16x8 wreg[16];
#pragma unroll
    for (int i = 0; i < 16; ++i)
      wreg[i] = *(const bf16x8*)&w2p[((size_t)cg * 512 + (w * 16 + i) * 4 + l4) * 128 + l15 * 8];
    if (lmode) xbar_wait(xarr, xk, tc);
    else       gbar_wait(arr, gflag, j, tc);

    // ---------- Phase C: hx_new[16g.., 16cg..] = a @ W2 + b2 + hx (pure MFMA) ----------
    {
      f32x4 cac = {0.f, 0.f, 0.f, 0.f};
      if (lmode) {
#pragma unroll
        for (int i = 0; i < 16; ++i) {
          const int s2 = w * 16 + i;
          bf16x8 af = *(const bf16x8*)&abl[((s2 * 4 + g) * 64 + l) * 8];  // local L2
          cac = __builtin_amdgcn_mfma_f32_16x16x32_bf16(af, wreg[i], cac, 0, 0, 0);
        }
      } else {
#pragma unroll
        for (int i = 0; i < 16; ++i) {
          const int s2 = w * 16 + i;
          bf16x8 af = nt_ld16(&abf[((s2 * 4 + g) * 64 + l) * 8]);
          cac = __builtin_amdgcn_mfma_f32_16x16x32_bf16(af, wreg[i], cac, 0, 0, 0);
        }
      }
      *(f32x4*)&red[(w * 64 + l) * 4] = cac;
    }
    __syncthreads();
    if (w < 4) {                         // parallel epilogue: wave w handles r=w
      float s = 0.f;
#pragma unroll
      for (int w2 = 0; w2 < 8; ++w2) s += red[(w2 * 64 + l) * 4 + w];
      const int rw = l4 * 4 + w;         // row within block tile (0..15)
      const int row = g * 16 + rw;
      const int c = cg * 16 + l15;
      const float vNew = s + b2v + hxf32[row * ISZ + c];   // private, cached
      hxf32[row * ISZ + c] = vNew;
      out[((size_t)row * TT + t) * ISZ + c] = vNew;        // write-once, cached
      abuf[rw * 16 + l15] = (__bf16)vNew;                  // pack tile in LDS
    }
    __syncthreads();                     // tile complete in abuf
    if (tid < 32) {                      // publish hx tile: 32 packed 16B coh stores
      const int rw = tid >> 1, kg = tid & 1;
      bf16x8 vv = *(const bf16x8*)&abuf[rw * 16 + kg * 8];
      const int row = g * 16 + rw;
      const int c0w = cg * 16 + kg * 8;
      const int kh = c0w >> 5, lh = ((c0w >> 3) & 3) * 16 + (row & 15), mh = row >> 4;
      coh_st16(&hxbf[((kh * 4 + mh) * 64 + lh) * 8], vv);
    }
    ++tc; gbar_arrive(arr, j, tc);       // post-C arrive; stagers poll our arr line
  }
}

// ---------------- host ----------------
extern "C" void kernel_launch(void* const* d_in, const int* in_sizes, int n_in,
                              void* d_out, int out_size, void* d_ws, size_t ws_size,
                              hipStream_t stream) {
  const float* x       = (const float*)d_in[0];
  const float* W1      = (const float*)d_in[1];
  const float* b1      = (const float*)d_in[2];
  const float* ln_g    = (const float*)d_in[3];
  const float* ln_b    = (const float*)d_in[4];
  const float* W2      = (const float*)d_in[5];
  const float* b2      = (const float*)d_in[6];
  const float* init_hx = (const float*)d_in[7];
  float* out = (float*)d_out;

  char* ws = (char*)d_ws;
  __bf16* w1p     = (__bf16*)(ws);                       // 16 MB @ 0
  __bf16* w2p     = (__bf16*)(ws + 16777216ull);         // 8 MB
  __bf16* hbf     = (__bf16*)(ws + 25165824ull);         // 512 KB master h
  __bf16* abf     = (__bf16*)(ws + 25690112ull);         // 512 KB master a (fallback)
  __bf16* ablocal = (__bf16*)(ws + 26214400ull);         // 8 x 512 KB per-XCD a copies
  __bf16* hxbf    = (__bf16*)(ws + 30408704ull);         // 128 KB master hx
  float* hxf32    = (float*)(ws + 30539776ull);          // 256 KB
  unsigned* arr   = (unsigned*)(ws + 30801920ull);       // 32 KB arrival flags
  unsigned* gflag = (unsigned*)(ws + 30834688ull);       // 1 KB group flags
  unsigned* xarr  = (unsigned*)(ws + 30835712ull);       // 32 KB XCD-barrier flags
  unsigned* ticket= (unsigned*)(ws + 30868480ull);       // 128 B tickets
  __bf16* hxlocal = (__bf16*)(ws + 31457280ull);         // 8 x 128 KB per-XCD hx copies @ 30 MB
  __bf16* xbf     = (__bf16*)(ws + 33554432ull);         // 64 MB @ 32 MB
  const bool use_xbf = (ws_size >= 33554432ull + 67108864ull);

  prep_w1<<<4096, 256, 0, stream>>>(W1, w1p);
  prep_w2<<<2048, 256, 0, stream>>>(W2, w2p);
  prep_state<<<256, 256, 0, stream>>>(init_hx, hxf32, hxbf, arr);
  if (use_xbf) {
    prep_x<<<16384, 256, 0, stream>>>(x, xbf);
    rnn_persist<true><<<NBLK, NTHR, 0, stream>>>(
        x, b1, ln_g, ln_b, b2, out, w1p, w2p, xbf, hbf, abf, ablocal,
        hxlocal, hxbf, hxf32, arr, gflag, xarr, ticket);
  } else {
    rnn_persist<false><<<NBLK, NTHR, 0, stream>>>(
        x, b1, ln_g, ln_b, b2, out, w1p, w2p, xbf, hbf, abf, ablocal,
        hxlocal, hxbf, hxf32, arr, gflag, xarr, ticket);
  }
}

// Round 15
// 8044.862 us; speedup vs baseline: 1.0193x; 1.0193x over previous
//
#include <hip/hip_runtime.h>
#include <hip/hip_bf16.h>
#include <math.h>

typedef __bf16 bf16x8 __attribute__((ext_vector_type(8)));
typedef float f32x4 __attribute__((ext_vector_type(4)));
typedef unsigned long long u64;
typedef u64 u64x2 __attribute__((ext_vector_type(2)));

#define TT 512
#define ISZ 1024
#define HSZ 4096
#define NBLK 256
#define NTHR 512
#define LN_EPS 1e-6f
#define SCOPE_AGENT __HIP_MEMORY_SCOPE_AGENT

union U128 { u64 u[2]; u64x2 p; bf16x8 v; };

// consumer of remote-written data: non-temporal load (no allocate -> no staleness)
__device__ __forceinline__ bf16x8 nt_ld16(const __bf16* p) {
  U128 r;
  r.p = __builtin_nontemporal_load((const u64x2*)p);
  return r.v;
}
// producer to cross-XCD master buffers: relaxed agent write-through (validated R3-R14)
__device__ __forceinline__ void coh_st16(__bf16* p, bf16x8 v) {
  U128 r; r.v = v;
  u64* q = (u64*)p;
  __hip_atomic_store(q,     r.u[0], __ATOMIC_RELAXED, SCOPE_AGENT);
  __hip_atomic_store(q + 1, r.u[1], __ATOMIC_RELAXED, SCOPE_AGENT);
}

// exact-grade GELU: Abramowitz-Stegun 7.1.26 erf (|eps|<=1.5e-7), branchless
__device__ __forceinline__ float gelu_f(float v) {
  const float u = v * 0.70710678118654752f;
  const float x = fabsf(u);
  const float t = __builtin_amdgcn_rcpf(fmaf(0.3275911f, x, 1.0f));
  float p = fmaf(1.061405429f, t, -1.453152027f);
  p = fmaf(p, t, 1.421413741f);
  p = fmaf(p, t, -0.284496736f);
  p = fmaf(p, t, 0.254829592f);
  p = p * t;
  const float e = p * __expf(-x * x);
  const float erfv = copysignf(1.0f - e, u);
  return 0.5f * v * (1.0f + erfv);
}

// frag-image index shared by hbf / abf / ablocal: [s2 128][g 4][lane 64][kk 8]
__device__ __forceinline__ int frag_idx(int row, int u) {
  return (((u >> 2) * 4 + (row >> 4)) * 64 + (u & 3) * 16 + (row & 15)) * 8;
}

// ---------------- prep kernels ----------------
// w1p layout: [nblk 256][kgrp 256][col 16][kk 8] bf16  (64 KB per nblk = LDS image)
__global__ void prep_w1(const float* __restrict__ W1, __bf16* __restrict__ w1p) {
  int t = blockIdx.x * blockDim.x + threadIdx.x;   // 1048576 threads
  int k = t >> 9;
  int n8 = (t & 511) << 3;
  const float* src = W1 + (size_t)k * HSZ + n8;
  float4 f0 = *(const float4*)src;
  float4 f1 = *(const float4*)(src + 4);
  int kgrp = k >> 3, kk = k & 7;
  float vals[8] = {f0.x, f0.y, f0.z, f0.w, f1.x, f1.y, f1.z, f1.w};
#pragma unroll
  for (int i = 0; i < 8; ++i) {
    int n = n8 + i;
    int nb = n >> 4, col = n & 15;
    w1p[(size_t)nb * 32768 + kgrp * 128 + col * 8 + kk] = (__bf16)vals[i];
  }
}

// w2p layout: [cg 64][kgrp 512][col 16][kk 8] bf16
__global__ void prep_w2(const float* __restrict__ W2, __bf16* __restrict__ w2p) {
  int t = blockIdx.x * blockDim.x + threadIdx.x;   // 524288 threads
  int k = t >> 7;
  int n8 = (t & 127) << 3;
  const float* src = W2 + (size_t)k * ISZ + n8;
  float4 f0 = *(const float4*)src;
  float4 f1 = *(const float4*)(src + 4);
  int kgrp = k >> 3, kk = k & 7;
  float vals[8] = {f0.x, f0.y, f0.z, f0.w, f1.x, f1.y, f1.z, f1.w};
#pragma unroll
  for (int i = 0; i < 8; ++i) {
    int n = n8 + i;
    int cg = n >> 4, col = n & 15;
    w2p[(size_t)cg * 65536 + kgrp * 128 + col * 8 + kk] = (__bf16)vals[i];
  }
}

// xbf layout per t: [kh 32][m 4][lane 64][kk 8] bf16 (128 KB) — GEMM1 A-frag image
__global__ void prep_x(const float* __restrict__ x, __bf16* __restrict__ xbf) {
  int tid = blockIdx.x * blockDim.x + threadIdx.x;  // 4194304 threads
  int c8 = tid & 127;
  int t = (tid >> 7) & 511;
  int row = tid >> 16;
  const float* src = x + ((size_t)row * TT + t) * ISZ + c8 * 8;
  float4 f0 = *(const float4*)src;
  float4 f1 = *(const float4*)(src + 4);
  float vals[8] = {f0.x, f0.y, f0.z, f0.w, f1.x, f1.y, f1.z, f1.w};
  bf16x8 v;
#pragma unroll
  for (int i = 0; i < 8; ++i) v[i] = (__bf16)vals[i];
  int kh = c8 >> 2, lane = (c8 & 3) * 16 + (row & 15), m = row >> 4;
  *(bf16x8*)&xbf[(size_t)t * 65536 + (((kh * 4 + m) * 64 + lane) << 3)] = v;
}

// hxbf layout: [kh 32][m 4][lane 64][kk 8] bf16
__global__ void prep_state(const float* __restrict__ init_hx,
                           float* __restrict__ hxf32, __bf16* __restrict__ hxbf,
                           unsigned* __restrict__ syncbuf) {
  int t = blockIdx.x * blockDim.x + threadIdx.x;   // 65536 threads
  int row = t >> 10, c = t & 1023;
  float v = init_hx[c];
  hxf32[t] = v;
  int kh = c >> 5, l = ((c >> 3) & 3) * 16 + (row & 15), m = row >> 4;
  hxbf[((kh * 4 + m) * 64 + l) * 8 + (c & 7)] = (__bf16)v;
  if (t < 16672) syncbuf[t] = 0u;       // arr + gflag + xarr + tickets
}

// ---- fence-free 2-hop global barrier, split arrive/wait ----
__device__ __forceinline__ void gbar_arrive(unsigned* __restrict__ arr,
                                            int j, unsigned target) {
  __syncthreads();                       // drains each wave's own stores
  if (threadIdx.x == 0)
    __hip_atomic_store(&arr[j * 32], target, __ATOMIC_RELAXED, SCOPE_AGENT);
}
__device__ __forceinline__ void gbar_wait(unsigned* __restrict__ arr,
                                          unsigned* __restrict__ gflag,
                                          int j, unsigned target) {
  const int tid = threadIdx.x;
  if (j < 8 && tid < 32) {               // wave 0 of blocks 0..7: group aggregator
    const unsigned* p = &arr[(tid * 8 + j) * 32];
    int guard = 0;
    for (;;) {
      unsigned v = __hip_atomic_load(p, __ATOMIC_RELAXED, SCOPE_AGENT);
      if (__all(v >= target)) break;
      if (++guard > (1 << 20)) break;    // fail-safe: wrong answer beats a hang
      __builtin_amdgcn_s_sleep(1);
    }
    asm volatile("" ::: "memory");
    if (tid == 0)
      __hip_atomic_store(&gflag[j * 32], target, __ATOMIC_RELAXED, SCOPE_AGENT);
  }
  if (tid < 8) {                         // everyone: poll the 8 group flags
    const unsigned* p = &gflag[tid * 32];
    int guard = 0;
    for (;;) {
      unsigned v = __hip_atomic_load(p, __ATOMIC_RELAXED, SCOPE_AGENT);
      if (__all(v >= target)) break;
      if (++guard > (1 << 20)) break;
      __builtin_amdgcn_s_sleep(1);
    }
  }
  asm volatile("" ::: "memory");
  __syncthreads();
}
__device__ __forceinline__ void gbar(unsigned* __restrict__ arr,
                                     unsigned* __restrict__ gflag,
                                     int j, unsigned target) {
  gbar_arrive(arr, j, target);
  gbar_wait(arr, gflag, j, target);
}

// ---- flat 1-hop all-wave wait: wave w polls arrival lines 32w..32w+31 ----
// (2 lanes per line; __all over the wave = its 32-line slice done; syncthreads joins)
__device__ __forceinline__ void flat_wait_all(const unsigned* __restrict__ arr,
                                              unsigned target) {
  const int w = threadIdx.x >> 6, l = threadIdx.x & 63;
  const unsigned* p = &arr[(w * 32 + (l & 31)) * 32];
  int guard = 0;
  for (;;) {
    unsigned v = __hip_atomic_load(p, __ATOMIC_RELAXED, SCOPE_AGENT);
    if (__all(v >= target)) break;
    if (++guard > (1 << 20)) break;      // fail-safe: wrong answer beats a hang
    __builtin_amdgcn_s_sleep(1);
  }
  asm volatile("" ::: "memory");
  __syncthreads();
}

// ---- XCD-local 1-hop barrier, split arrive/wait ----
__device__ __forceinline__ void xbar_arrive(unsigned* __restrict__ xarr,
                                            int xk, int xrank, unsigned target) {
  __syncthreads();
  if (threadIdx.x == 0)
    __hip_atomic_store(&xarr[(xk * 32 + xrank) * 32], target, __ATOMIC_RELAXED, SCOPE_AGENT);
}
__device__ __forceinline__ void xbar_wait(unsigned* __restrict__ xarr,
                                          int xk, unsigned target) {
  const int tid = threadIdx.x;
  if (tid < 32) {
    const unsigned* p = &xarr[(xk * 32 + tid) * 32];
    int guard = 0;
    for (;;) {
      unsigned v = __hip_atomic_load(p, __ATOMIC_RELAXED, SCOPE_AGENT);
      if (__all(v >= target)) break;
      if (++guard > (1 << 20)) break;
      __builtin_amdgcn_s_sleep(1);
    }
  }
  asm volatile("" ::: "memory");
  __syncthreads();
}

// ---------------- persistent RNN kernel ----------------
template <bool USE_XBF>
__global__ __launch_bounds__(NTHR, 1) void rnn_persist(
    const float* __restrict__ x, const float* __restrict__ b1,
    const float* __restrict__ ln_g, const float* __restrict__ ln_b,
    const float* __restrict__ b2, float* __restrict__ out,
    const __bf16* __restrict__ w1p, const __bf16* __restrict__ w2p,
    const __bf16* __restrict__ xbf,
    __bf16* __restrict__ hbf, __bf16* __restrict__ abf,
    __bf16* __restrict__ ablocal, __bf16* __restrict__ hxlocal,
    __bf16* __restrict__ hxbf,
    float* __restrict__ hxf32, unsigned* __restrict__ arr,
    unsigned* __restrict__ gflag, unsigned* __restrict__ xarr,
    unsigned* __restrict__ ticket)
{
  __shared__ __bf16 w1s[32768];   // 64 KB [kgrp 256][col 16][kk 8]
  __shared__ float red[8192];     // 32 KB cross-wave reduction + stat partials
  __shared__ __bf16 abuf[1024];   // 2 KB h-tile repack
  __shared__ int sh_meta[4];      // xk, xrank, lmode

  const int j = blockIdx.x;
  const int tid = threadIdx.x;
  const int w = tid >> 6;
  const int l = tid & 63;
  const int l4 = l >> 4, l15 = l & 15;

  // physical-XCD ticket (once per kernel)
  if (tid == 0) {
    unsigned xcd = ((unsigned)__builtin_amdgcn_s_getreg(63508)) & 7u;  // HW_REG_XCC_ID
    unsigned r = __hip_atomic_fetch_add(&ticket[xcd], 1u, __ATOMIC_RELAXED, SCOPE_AGENT);
    sh_meta[0] = (int)xcd;
    sh_meta[1] = (int)r;
  }

  { // stage this block's W1 slice into LDS (one-time)
    const bf16x8* src = (const bf16x8*)(w1p + (size_t)j * 32768);
    bf16x8* dst = (bf16x8*)w1s;
#pragma unroll
    for (int i = 0; i < 8; ++i) dst[tid + i * 512] = src[tid + i * 512];
  }

  unsigned tc = 1;
  gbar(arr, gflag, j, tc);               // all tickets taken, W1 staged; arr=1 everywhere

  if (tid == 0) {
    int ok = 1;
#pragma unroll
    for (int i = 0; i < 8; ++i)
      ok &= (__hip_atomic_load(&ticket[i], __ATOMIC_RELAXED, SCOPE_AGENT) == 32u);
    sh_meta[2] = ok && (sh_meta[1] < 32);
  }
  __syncthreads();
  const int xk = sh_meta[0];
  const int xrank = sh_meta[1];
  const bool lmode = (sh_meta[2] != 0);
  __bf16* abl = ablocal + (size_t)xk * 262144;   // this XCD's 512 KB abf copy
  __bf16* hxl = hxlocal + (size_t)xk * 65536;    // this XCD's 128 KB hx copy

  const float b1v = b1[j * 16 + l15];
  const int g = j >> 6, cg = j & 63;     // phase-C tile: rows 16g.., cols 16cg..
  const float b2v = b2[cg * 16 + l15];

  // fallback path: this wave's 32 hx-producer blocks
  const int prodj = ((l >> 3) & 3) * 64 + w * 8 + (l & 7);
  // lmode: the 8 producers of our staging slice (kh = xrank, cols xrank*32..+32):
  //   c in [xrank*32, xrank*32+32) -> cg in {2*xrank, 2*xrank+1}, g = 0..3
  const int stgj = ((tid >> 1) & 3) * 64 + 2 * xrank + (tid & 1);  // valid for tid<8

  // x-half of phase A for step tt, K-slices [i0,i1) of this wave's 4; i0==0 zero-inits
  auto do_xhalf_range = [&](int tt, f32x4* hac, int i0, int i1) {
    if (i0 == 0) {
#pragma unroll
      for (int m = 0; m < 4; ++m) hac[m] = (f32x4){0.f, 0.f, 0.f, 0.f};
    }
    for (int i = i0; i < i1; ++i) {      // ks = w*4+i  (0..31 over 8 waves)
      const int ks = w * 4 + i;
      bf16x8 bfr = *(const bf16x8*)&w1s[((4 * ks + l4) * 16 + l15) * 8];
      if (USE_XBF) {
        const __bf16* xb = xbf + (size_t)tt * 65536 + (size_t)ks * 2048;
#pragma unroll
        for (int m = 0; m < 4; ++m) {
          bf16x8 af = *(const bf16x8*)&xb[(m * 64 + l) * 8];
          hac[m] = __builtin_amdgcn_mfma_f32_16x16x32_bf16(af, bfr, hac[m], 0, 0, 0);
        }
      } else {
        const int k = ks * 32 + l4 * 8;
#pragma unroll
        for (int m = 0; m < 4; ++m) {
          const int row = m * 16 + l15;
          const float* p = x + ((size_t)row * TT + tt) * ISZ + k;
          float4 f0 = *(const float4*)p;
          float4 f1 = *(const float4*)(p + 4);
          bf16x8 af;
          af[0] = (__bf16)f0.x; af[1] = (__bf16)f0.y;
          af[2] = (__bf16)f0.z; af[3] = (__bf16)f0.w;
          af[4] = (__bf16)f1.x; af[5] = (__bf16)f1.y;
          af[6] = (__bf16)f1.z; af[7] = (__bf16)f1.w;
          hac[m] = __builtin_amdgcn_mfma_f32_16x16x32_bf16(af, bfr, hac[m], 0, 0, 0);
        }
      }
    }
  };

  for (int t = 0; t < TT; ++t) {
    f32x4 hac[4];
    if (lmode) {
      // ---------- x-half part 1 (2 K-slices): covers the stage-poll wait ----------
      do_xhalf_range(t, hac, 0, 2);
      // ---------- stage hx slice kh=xrank into XCD-local copy ----------
      if (tid < 8) {                     // poll our slice's 8 producers (post-C(t-1))
        const unsigned* p = &arr[stgj * 32];
        int guard = 0;
        for (;;) {
          unsigned v = __hip_atomic_load(p, __ATOMIC_RELAXED, SCOPE_AGENT);
          if (__all(v >= tc)) break;
          if (++guard > (1 << 20)) break;  // fail-safe
          __builtin_amdgcn_s_sleep(1);
        }
      }
      asm volatile("" ::: "memory");
      __syncthreads();                   // stage readers wait for the poll
      if (tid < 256) {                   // copy 4 KB slice: master(nt) -> local(cached)
        const int off = xrank * 2048 + tid * 8;
        bf16x8 v = nt_ld16(hxbf + off);
        *(bf16x8*)(hxl + off) = v;       // normal store: dirty line in OUR L2
      }
      ++tc; xbar_arrive(xarr, xk, xrank, tc);   // syncthreads drains the stores
      // ---------- x-half part 2 (2 K-slices): covers the xbar2 wait ----------
      do_xhalf_range(t, hac, 2, 4);
      xbar_wait(xarr, xk, tc);           // full hx staged in local L2

      // ---------- Phase A, hx-half: normal loads, local L2 hits ----------
#pragma unroll
      for (int i = 0; i < 4; ++i) {      // kh = w*4 .. w*4+4
        const int kh = w * 4 + i;
        bf16x8 bfr = *(const bf16x8*)&w1s[((4 * (32 + kh) + l4) * 16 + l15) * 8];
#pragma unroll
        for (int m = 0; m < 4; ++m) {
          bf16x8 af = *(const bf16x8*)&hxl[((kh * 4 + m) * 64 + l) * 8];
          hac[m] = __builtin_amdgcn_mfma_f32_16x16x32_bf16(af, bfr, hac[m], 0, 0, 0);
        }
      }
    } else {
      // ---------- fallback: R9 path (x-half, direct poll, nt hx reads) ----------
      do_xhalf_range(t, hac, 0, 4);
      {
        const unsigned* p = &arr[prodj * 32];
        int guard = 0;
        for (;;) {
          unsigned v = __hip_atomic_load(p, __ATOMIC_RELAXED, SCOPE_AGENT);
          if (__all(v >= tc)) break;
          if (++guard > (1 << 20)) break;
          __builtin_amdgcn_s_sleep(1);
        }
        asm volatile("" ::: "memory");
      }
      ++tc;                              // keep tc aligned with lmode's xbar2 bump
#pragma unroll
      for (int i = 0; i < 4; ++i) {
        const int kh = w * 4 + i;
        bf16x8 bfr = *(const bf16x8*)&w1s[((4 * (32 + kh) + l4) * 16 + l15) * 8];
#pragma unroll
        for (int m = 0; m < 4; ++m) {
          bf16x8 af = nt_ld16(&hxbf[((kh * 4 + m) * 64 + l) * 8]);
          hac[m] = __builtin_amdgcn_mfma_f32_16x16x32_bf16(af, bfr, hac[m], 0, 0, 0);
        }
      }
    }

#pragma unroll
    for (int m = 0; m < 4; ++m)
      *(f32x4*)&red[((w * 4 + m) * 64 + l) * 4] = hac[m];
    __syncthreads();
    if (w < 4) {                         // wave w owns m-tile w: rows 16w..16w+16
      f32x4 h = *(const f32x4*)&red[((0 * 4 + w) * 64 + l) * 4];
#pragma unroll
      for (int s = 1; s < 8; ++s)
        h += *(const f32x4*)&red[((s * 4 + w) * 64 + l) * 4];
#pragma unroll
      for (int r = 0; r < 4; ++r)        // C layout: col=l15, row=16w+4*l4+r
        abuf[(w * 16 + l4 * 4 + r) * 16 + l15] = (__bf16)(h[r] + b1v);
    }
    __syncthreads();
    if (tid < 128) {                     // h-tile -> hbf master frag image (coherent)
      const int m = tid >> 5, q2s = (tid >> 4) & 1, rr = tid & 15;
      bf16x8 vv = *(const bf16x8*)&abuf[(m * 16 + rr) * 16 + q2s * 8];
      const int k2 = j >> 1, q2 = (j & 1) * 2 + q2s;
      coh_st16(&hbf[(((k2 * 4 + m) * 64) + q2 * 16 + rr) * 8], vv);
    }
    // ---------- post-A: arrive + flat 1-hop all-wave wait (no aggregator hop) ----------
    ++tc;
    gbar_arrive(arr, j, tc);
    flat_wait_all(arr, tc);              // h globally visible

    // ---------- Phase B: a = gelu(LN(h)) computed once per XCD copy ----------
    if (lmode) {
      const int u = tid;
      const int R0 = xrank * 2, R1 = R0 + 1;
      const int i0 = frag_idx(R0, u), i1 = frag_idx(R1, u);
      bf16x8 h0 = nt_ld16(hbf + i0);
      bf16x8 h1 = nt_ld16(hbf + i1);
      float s0 = 0.f, q0 = 0.f, s1 = 0.f, q1 = 0.f;
#pragma unroll
      for (int e = 0; e < 8; ++e) {
        float v0 = (float)h0[e], v1 = (float)h1[e];
        s0 += v0; q0 += v0 * v0; s1 += v1; q1 += v1 * v1;
      }
#pragma unroll
      for (int m = 1; m < 64; m <<= 1) {
        s0 += __shfl_xor(s0, m, 64); q0 += __shfl_xor(q0, m, 64);
        s1 += __shfl_xor(s1, m, 64); q1 += __shfl_xor(q1, m, 64);
      }
      if (l == 0) *(f32x4*)&red[4096 + w * 4] = (f32x4){s0, q0, s1, q1};
      __syncthreads();
      float S0 = 0.f, Q0 = 0.f, S1 = 0.f, Q1 = 0.f;
#pragma unroll
      for (int w2 = 0; w2 < 8; ++w2) {
        f32x4 p = *(const f32x4*)&red[4096 + w2 * 4];
        S0 += p[0]; Q0 += p[1]; S1 += p[2]; Q1 += p[3];
      }
      const float mu0 = S0 * (1.f / 4096.f), mu1 = S1 * (1.f / 4096.f);
      const float rs0 = rsqrtf(Q0 * (1.f / 4096.f) - mu0 * mu0 + LN_EPS);
      const float rs1 = rsqrtf(Q1 * (1.f / 4096.f) - mu1 * mu1 + LN_EPS);
      const int c0 = (u >> 2) * 32 + (u & 3) * 8;
      float4 ga = *(const float4*)(ln_g + c0), gb = *(const float4*)(ln_g + c0 + 4);
      float4 ea = *(const float4*)(ln_b + c0), eb = *(const float4*)(ln_b + c0 + 4);
      float gk[8] = {ga.x, ga.y, ga.z, ga.w, gb.x, gb.y, gb.z, gb.w};
      float ek[8] = {ea.x, ea.y, ea.z, ea.w, eb.x, eb.y, eb.z, eb.w};
      bf16x8 a0, a1;
#pragma unroll
      for (int e = 0; e < 8; ++e) {
        a0[e] = (__bf16)gelu_f(((float)h0[e] - mu0) * rs0 * gk[e] + ek[e]);
        a1[e] = (__bf16)gelu_f(((float)h1[e] - mu1) * rs1 * gk[e] + ek[e]);
      }
      *(bf16x8*)(abl + i0) = a0;         // normal cached stores: XCD-local copy
      *(bf16x8*)(abl + i1) = a1;
    } else {                             // fallback: gelu once into master abf
      const int u = tid;
      const int R = j >> 2, q = j & 3;
      const int iR = frag_idx(R, u);
      bf16x8 hv = nt_ld16(hbf + iR);
      float s0 = 0.f, q0 = 0.f;
#pragma unroll
      for (int e = 0; e < 8; ++e) { float v = (float)hv[e]; s0 += v; q0 += v * v; }
#pragma unroll
      for (int m = 1; m < 64; m <<= 1) {
        s0 += __shfl_xor(s0, m, 64); q0 += __shfl_xor(q0, m, 64);
      }
      if (l == 0) { red[4096 + w * 2] = s0; red[4096 + w * 2 + 1] = q0; }
      __syncthreads();
      float S = 0.f, Q = 0.f;
#pragma unroll
      for (int w2 = 0; w2 < 8; ++w2) { S += red[4096 + w2 * 2]; Q += red[4096 + w2 * 2 + 1]; }
      const float mu = S * (1.f / 4096.f);
      const float rs = rsqrtf(Q * (1.f / 4096.f) - mu * mu + LN_EPS);
      if ((tid >> 7) == q) {
        const int c0 = (u >> 2) * 32 + (u & 3) * 8;
        float4 ga = *(const float4*)(ln_g + c0), gb = *(const float4*)(ln_g + c0 + 4);
        float4 ea = *(const float4*)(ln_b + c0), eb = *(const float4*)(ln_b + c0 + 4);
        float gk[8] = {ga.x, ga.y, ga.z, ga.w, gb.x, gb.y, gb.z, gb.w};
        float ek[8] = {ea.x, ea.y, ea.z, ea.w, eb.x, eb.y, eb.z, eb.w};
        bf16x8 av;
#pragma unroll
        for (int e = 0; e < 8; ++e)
          av[e] = (__bf16)gelu_f(((float)hv[e] - mu) * rs * gk[e] + ek[e]);
        coh_st16(abf + iR, av);
      }
    }

    // ---------- B->C sync with w2p prefetch hidden between arrive and wait ----------
    ++tc;
    if (lmode) xbar_arrive(xarr, xk, xrank, tc);
    else       gbar_arrive(arr, j, tc);
    bf16x8 wreg[16];
#pragma unroll
    for (int i = 0; i < 16; ++i)
      wreg[i] = *(const bf16x8*)&w2p[((size_t)cg * 512 + (w * 16 + i) * 4 + l4) * 128 + l15 * 8];
    if (lmode) xbar_wait(xarr, xk, tc);
    else       gbar_wait(arr, gflag, j, tc);

    // ---------- Phase C: hx_new[16g.., 16cg..] = a @ W2 + b2 + hx (pure MFMA) ----------
    {
      f32x4 cac = {0.f, 0.f, 0.f, 0.f};
      if (lmode) {
#pragma unroll
        for (int i = 0; i < 16; ++i) {
          const int s2 = w * 16 + i;
          bf16x8 af = *(const bf16x8*)&abl[((s2 * 4 + g) * 64 + l) * 8];  // local L2
          cac = __builtin_amdgcn_mfma_f32_16x16x32_bf16(af, wreg[i], cac, 0, 0, 0);
        }
      } else {
#pragma unroll
        for (int i = 0; i < 16; ++i) {
          const int s2 = w * 16 + i;
          bf16x8 af = nt_ld16(&abf[((s2 * 4 + g) * 64 + l) * 8]);
          cac = __builtin_amdgcn_mfma_f32_16x16x32_bf16(af, wreg[i], cac, 0, 0, 0);
        }
      }
      *(f32x4*)&red[(w * 64 + l) * 4] = cac;
    }
    __syncthreads();
    if (w < 4) {                         // parallel epilogue: wave w handles r=w
      float s = 0.f;
#pragma unroll
      for (int w2 = 0; w2 < 8; ++w2) s += red[(w2 * 64 + l) * 4 + w];
      const int row = g * 16 + l4 * 4 + w;
      const int c = cg * 16 + l15;
      const float vNew = s + b2v + hxf32[row * ISZ + c];   // private, cached
      hxf32[row * ISZ + c] = vNew;
      out[((size_t)row * TT + t) * ISZ + c] = vNew;        // write-once, cached
      const int kh = c >> 5, lh = ((c >> 3) & 3) * 16 + (row & 15), mh = row >> 4;
      union { __bf16 b; unsigned short s16; } cv; cv.b = (__bf16)vNew;
      __hip_atomic_store((unsigned short*)&hxbf[((kh * 4 + mh) * 64 + lh) * 8 + (c & 7)],
                         cv.s16, __ATOMIC_RELAXED, SCOPE_AGENT);
    }
    ++tc; gbar_arrive(arr, j, tc);       // post-C arrive; stagers poll our arr line
  }
}

// ---------------- host ----------------
extern "C" void kernel_launch(void* const* d_in, const int* in_sizes, int n_in,
                              void* d_out, int out_size, void* d_ws, size_t ws_size,
                              hipStream_t stream) {
  const float* x       = (const float*)d_in[0];
  const float* W1      = (const float*)d_in[1];
  const float* b1      = (const float*)d_in[2];
  const float* ln_g    = (const float*)d_in[3];
  const float* ln_b    = (const float*)d_in[4];
  const float* W2      = (const float*)d_in[5];
  const float* b2      = (const float*)d_in[6];
  const float* init_hx = (const float*)d_in[7];
  float* out = (float*)d_out;

  char* ws = (char*)d_ws;
  __bf16* w1p     = (__bf16*)(ws);                       // 16 MB @ 0
  __bf16* w2p     = (__bf16*)(ws + 16777216ull);         // 8 MB
  __bf16* hbf     = (__bf16*)(ws + 25165824ull);         // 512 KB master h
  __bf16* abf     = (__bf16*)(ws + 25690112ull);         // 512 KB master a (fallback)
  __bf16* ablocal = (__bf16*)(ws + 26214400ull);         // 8 x 512 KB per-XCD a copies
  __bf16* hxbf    = (__bf16*)(ws + 30408704ull);         // 128 KB master hx
  float* hxf32    = (float*)(ws + 30539776ull);          // 256 KB
  unsigned* arr   = (unsigned*)(ws + 30801920ull);       // 32 KB arrival flags
  unsigned* gflag = (unsigned*)(ws + 30834688ull);       // 1 KB group flags
  unsigned* xarr  = (unsigned*)(ws + 30835712ull);       // 32 KB XCD-barrier flags
  unsigned* ticket= (unsigned*)(ws + 30868480ull);       // 128 B tickets
  __bf16* hxlocal = (__bf16*)(ws + 31457280ull);         // 8 x 128 KB per-XCD hx copies @ 30 MB
  __bf16* xbf     = (__bf16*)(ws + 33554432ull);         // 64 MB @ 32 MB
  const bool use_xbf = (ws_size >= 33554432ull + 67108864ull);

  prep_w1<<<4096, 256, 0, stream>>>(W1, w1p);
  prep_w2<<<2048, 256, 0, stream>>>(W2, w2p);
  prep_state<<<256, 256, 0, stream>>>(init_hx, hxf32, hxbf, arr);
  if (use_xbf) {
    prep_x<<<16384, 256, 0, stream>>>(x, xbf);
    rnn_persist<true><<<NBLK, NTHR, 0, stream>>>(
        x, b1, ln_g, ln_b, b2, out, w1p, w2p, xbf, hbf, abf, ablocal,
        hxlocal, hxbf, hxf32, arr, gflag, xarr, ticket);
  } else {
    rnn_persist<false><<<NBLK, NTHR, 0, stream>>>(
        x, b1, ln_g, ln_b, b2, out, w1p, w2p, xbf, hbf, abf, ablocal,
        hxlocal, hxbf, hxf32, arr, gflag, xarr, ticket);
  }
}

// Round 16
// 7945.799 us; speedup vs baseline: 1.0320x; 1.0125x over previous
//
#include <hip/hip_runtime.h>
#include <hip/hip_bf16.h>
#include <math.h>

typedef __bf16 bf16x8 __attribute__((ext_vector_type(8)));
typedef float f32x4 __attribute__((ext_vector_type(4)));
typedef unsigned long long u64;
typedef u64 u64x2 __attribute__((ext_vector_type(2)));

#define TT 512
#define ISZ 1024
#define HSZ 4096
#define NBLK 256
#define NTHR 512
#define LN_EPS 1e-6f
#define SCOPE_AGENT __HIP_MEMORY_SCOPE_AGENT

union U128 { u64 u[2]; u64x2 p; bf16x8 v; };

// consumer of remote-written data: non-temporal load (no allocate -> no staleness)
__device__ __forceinline__ bf16x8 nt_ld16(const __bf16* p) {
  U128 r;
  r.p = __builtin_nontemporal_load((const u64x2*)p);
  return r.v;
}
// producer to cross-XCD master buffers: relaxed agent write-through (validated R3-R15)
__device__ __forceinline__ void coh_st16(__bf16* p, bf16x8 v) {
  U128 r; r.v = v;
  u64* q = (u64*)p;
  __hip_atomic_store(q,     r.u[0], __ATOMIC_RELAXED, SCOPE_AGENT);
  __hip_atomic_store(q + 1, r.u[1], __ATOMIC_RELAXED, SCOPE_AGENT);
}

// exact-grade GELU: Abramowitz-Stegun 7.1.26 erf (|eps|<=1.5e-7), branchless
__device__ __forceinline__ float gelu_f(float v) {
  const float u = v * 0.70710678118654752f;
  const float x = fabsf(u);
  const float t = __builtin_amdgcn_rcpf(fmaf(0.3275911f, x, 1.0f));
  float p = fmaf(1.061405429f, t, -1.453152027f);
  p = fmaf(p, t, 1.421413741f);
  p = fmaf(p, t, -0.284496736f);
  p = fmaf(p, t, 0.254829592f);
  p = p * t;
  const float e = p * __expf(-x * x);
  const float erfv = copysignf(1.0f - e, u);
  return 0.5f * v * (1.0f + erfv);
}

// frag-image index shared by hbf / abf / ablocal: [s2 128][g 4][lane 64][kk 8]
__device__ __forceinline__ int frag_idx(int row, int u) {
  return (((u >> 2) * 4 + (row >> 4)) * 64 + (u & 3) * 16 + (row & 15)) * 8;
}

// ---------------- prep kernels ----------------
// w1p layout: [nblk 256][kgrp 256][col 16][kk 8] bf16  (64 KB per nblk = LDS image)
__global__ void prep_w1(const float* __restrict__ W1, __bf16* __restrict__ w1p) {
  int t = blockIdx.x * blockDim.x + threadIdx.x;   // 1048576 threads
  int k = t >> 9;
  int n8 = (t & 511) << 3;
  const float* src = W1 + (size_t)k * HSZ + n8;
  float4 f0 = *(const float4*)src;
  float4 f1 = *(const float4*)(src + 4);
  int kgrp = k >> 3, kk = k & 7;
  float vals[8] = {f0.x, f0.y, f0.z, f0.w, f1.x, f1.y, f1.z, f1.w};
#pragma unroll
  for (int i = 0; i < 8; ++i) {
    int n = n8 + i;
    int nb = n >> 4, col = n & 15;
    w1p[(size_t)nb * 32768 + kgrp * 128 + col * 8 + kk] = (__bf16)vals[i];
  }
}

// w2p layout: [cg 64][kgrp 512][col 16][kk 8] bf16
__global__ void prep_w2(const float* __restrict__ W2, __bf16* __restrict__ w2p) {
  int t = blockIdx.x * blockDim.x + threadIdx.x;   // 524288 threads
  int k = t >> 7;
  int n8 = (t & 127) << 3;
  const float* src = W2 + (size_t)k * ISZ + n8;
  float4 f0 = *(const float4*)src;
  float4 f1 = *(const float4*)(src + 4);
  int kgrp = k >> 3, kk = k & 7;
  float vals[8] = {f0.x, f0.y, f0.z, f0.w, f1.x, f1.y, f1.z, f1.w};
#pragma unroll
  for (int i = 0; i < 8; ++i) {
    int n = n8 + i;
    int cg = n >> 4, col = n & 15;
    w2p[(size_t)cg * 65536 + kgrp * 128 + col * 8 + kk] = (__bf16)vals[i];
  }
}

// xbf layout per t: [kh 32][m 4][lane 64][kk 8] bf16 (128 KB) — GEMM1 A-frag image
__global__ void prep_x(const float* __restrict__ x, __bf16* __restrict__ xbf) {
  int tid = blockIdx.x * blockDim.x + threadIdx.x;  // 4194304 threads
  int c8 = tid & 127;
  int t = (tid >> 7) & 511;
  int row = tid >> 16;
  const float* src = x + ((size_t)row * TT + t) * ISZ + c8 * 8;
  float4 f0 = *(const float4*)src;
  float4 f1 = *(const float4*)(src + 4);
  float vals[8] = {f0.x, f0.y, f0.z, f0.w, f1.x, f1.y, f1.z, f1.w};
  bf16x8 v;
#pragma unroll
  for (int i = 0; i < 8; ++i) v[i] = (__bf16)vals[i];
  int kh = c8 >> 2, lane = (c8 & 3) * 16 + (row & 15), m = row >> 4;
  *(bf16x8*)&xbf[(size_t)t * 65536 + (((kh * 4 + m) * 64 + lane) << 3)] = v;
}

// hxbf layout: [kh 32][m 4][lane 64][kk 8] bf16
__global__ void prep_state(const float* __restrict__ init_hx,
                           float* __restrict__ hxf32, __bf16* __restrict__ hxbf,
                           unsigned* __restrict__ syncbuf) {
  int t = blockIdx.x * blockDim.x + threadIdx.x;   // 65536 threads
  int row = t >> 10, c = t & 1023;
  float v = init_hx[c];
  hxf32[t] = v;
  int kh = c >> 5, l = ((c >> 3) & 3) * 16 + (row & 15), m = row >> 4;
  hxbf[((kh * 4 + m) * 64 + l) * 8 + (c & 7)] = (__bf16)v;
  if (t < 16672) syncbuf[t] = 0u;       // arr + gflag + xarr + tickets
}

// ---- fence-free 2-hop global barrier, split arrive/wait ----
__device__ __forceinline__ void gbar_arrive(unsigned* __restrict__ arr,
                                            int j, unsigned target) {
  __syncthreads();                       // drains each wave's own stores
  if (threadIdx.x == 0)
    __hip_atomic_store(&arr[j * 32], target, __ATOMIC_RELAXED, SCOPE_AGENT);
}
__device__ __forceinline__ void gbar_wait(unsigned* __restrict__ arr,
                                          unsigned* __restrict__ gflag,
                                          int j, unsigned target) {
  const int tid = threadIdx.x;
  if (j < 8 && tid < 32) {               // wave 0 of blocks 0..7: group aggregator
    const unsigned* p = &arr[(tid * 8 + j) * 32];
    int guard = 0;
    for (;;) {
      unsigned v = __hip_atomic_load(p, __ATOMIC_RELAXED, SCOPE_AGENT);
      if (__all(v >= target)) break;
      if (++guard > (1 << 20)) break;    // fail-safe: wrong answer beats a hang
      __builtin_amdgcn_s_sleep(1);
    }
    asm volatile("" ::: "memory");
    if (tid == 0)
      __hip_atomic_store(&gflag[j * 32], target, __ATOMIC_RELAXED, SCOPE_AGENT);
  }
  if (tid < 8) {                         // everyone: poll the 8 group flags
    const unsigned* p = &gflag[tid * 32];
    int guard = 0;
    for (;;) {
      unsigned v = __hip_atomic_load(p, __ATOMIC_RELAXED, SCOPE_AGENT);
      if (__all(v >= target)) break;
      if (++guard > (1 << 20)) break;
      __builtin_amdgcn_s_sleep(1);
    }
  }
  asm volatile("" ::: "memory");
  __syncthreads();
}
__device__ __forceinline__ void gbar(unsigned* __restrict__ arr,
                                     unsigned* __restrict__ gflag,
                                     int j, unsigned target) {
  gbar_arrive(arr, j, target);
  gbar_wait(arr, gflag, j, target);
}

// ---- flat 1-hop all-wave wait: wave w polls arrival lines 32w..32w+31 ----
// (2 lanes per line; __all over the wave = its 32-line slice done; syncthreads joins)
__device__ __forceinline__ void flat_wait_all(const unsigned* __restrict__ arr,
                                              unsigned target) {
  const int w = threadIdx.x >> 6, l = threadIdx.x & 63;
  const unsigned* p = &arr[(w * 32 + (l & 31)) * 32];
  int guard = 0;
  for (;;) {
    unsigned v = __hip_atomic_load(p, __ATOMIC_RELAXED, SCOPE_AGENT);
    if (__all(v >= target)) break;
    if (++guard > (1 << 20)) break;      // fail-safe: wrong answer beats a hang
    __builtin_amdgcn_s_sleep(1);
  }
  asm volatile("" ::: "memory");
  __syncthreads();
}

// ---- XCD-local 1-hop barrier, split arrive/wait ----
__device__ __forceinline__ void xbar_arrive(unsigned* __restrict__ xarr,
                                            int xk, int xrank, unsigned target) {
  __syncthreads();
  if (threadIdx.x == 0)
    __hip_atomic_store(&xarr[(xk * 32 + xrank) * 32], target, __ATOMIC_RELAXED, SCOPE_AGENT);
}
__device__ __forceinline__ void xbar_wait(unsigned* __restrict__ xarr,
                                          int xk, unsigned target) {
  const int tid = threadIdx.x;
  if (tid < 32) {
    const unsigned* p = &xarr[(xk * 32 + tid) * 32];
    int guard = 0;
    for (;;) {
      unsigned v = __hip_atomic_load(p, __ATOMIC_RELAXED, SCOPE_AGENT);
      if (__all(v >= target)) break;
      if (++guard > (1 << 20)) break;
      __builtin_amdgcn_s_sleep(1);
    }
  }
  asm volatile("" ::: "memory");
  __syncthreads();
}

// ---------------- persistent RNN kernel ----------------
template <bool USE_XBF>
__global__ __launch_bounds__(NTHR, 1) void rnn_persist(
    const float* __restrict__ x, const float* __restrict__ b1,
    const float* __restrict__ ln_g, const float* __restrict__ ln_b,
    const float* __restrict__ b2, float* __restrict__ out,
    const __bf16* __restrict__ w1p, const __bf16* __restrict__ w2p,
    const __bf16* __restrict__ xbf,
    __bf16* __restrict__ hbf, __bf16* __restrict__ abf,
    __bf16* __restrict__ ablocal, __bf16* __restrict__ hxlocal,
    __bf16* __restrict__ hxbf,
    float* __restrict__ hxf32, unsigned* __restrict__ arr,
    unsigned* __restrict__ gflag, unsigned* __restrict__ xarr,
    unsigned* __restrict__ ticket)
{
  __shared__ __bf16 w1s[32768];   // 64 KB [kgrp 256][col 16][kk 8]
  __shared__ float red[8192];     // 32 KB cross-wave reduction + stat partials
  __shared__ __bf16 abuf[1024];   // 2 KB h-tile repack
  __shared__ int sh_meta[4];      // xk, xrank, lmode

  const int j = blockIdx.x;
  const int tid = threadIdx.x;
  const int w = tid >> 6;
  const int l = tid & 63;
  const int l4 = l >> 4, l15 = l & 15;

  // physical-XCD ticket (once per kernel)
  if (tid == 0) {
    unsigned xcd = ((unsigned)__builtin_amdgcn_s_getreg(63508)) & 7u;  // HW_REG_XCC_ID
    unsigned r = __hip_atomic_fetch_add(&ticket[xcd], 1u, __ATOMIC_RELAXED, SCOPE_AGENT);
    sh_meta[0] = (int)xcd;
    sh_meta[1] = (int)r;
  }

  { // stage this block's W1 slice into LDS (one-time)
    const bf16x8* src = (const bf16x8*)(w1p + (size_t)j * 32768);
    bf16x8* dst = (bf16x8*)w1s;
#pragma unroll
    for (int i = 0; i < 8; ++i) dst[tid + i * 512] = src[tid + i * 512];
  }

  unsigned tc = 1;
  gbar(arr, gflag, j, tc);               // all tickets taken, W1 staged; arr=1 everywhere

  if (tid == 0) {
    int ok = 1;
#pragma unroll
    for (int i = 0; i < 8; ++i)
      ok &= (__hip_atomic_load(&ticket[i], __ATOMIC_RELAXED, SCOPE_AGENT) == 32u);
    sh_meta[2] = ok && (sh_meta[1] < 32);
  }
  __syncthreads();
  const int xk = sh_meta[0];
  const int xrank = sh_meta[1];
  const bool lmode = (sh_meta[2] != 0);
  __bf16* abl = ablocal + (size_t)xk * 262144;   // this XCD's 512 KB abf copy
  __bf16* hxl = hxlocal + (size_t)xk * 65536;    // this XCD's 128 KB hx copy

  const float b1v = b1[j * 16 + l15];
  const int g = j >> 6, cg = j & 63;     // phase-C tile: rows 16g.., cols 16cg..
  const float b2v = b2[cg * 16 + l15];

  // fallback path: this wave's 32 hx-producer blocks
  const int prodj = ((l >> 3) & 3) * 64 + w * 8 + (l & 7);
  // lmode: the 8 producers of our staging slice (kh = xrank, cols xrank*32..+32):
  //   c in [xrank*32, xrank*32+32) -> cg in {2*xrank, 2*xrank+1}, g = 0..3
  const int stgj = ((tid >> 1) & 3) * 64 + 2 * xrank + (tid & 1);  // valid for tid<8

  // x-half of phase A for step tt, K-slices [i0,i1) of this wave's 4; i0==0 zero-inits
  auto do_xhalf_range = [&](int tt, f32x4* hac, int i0, int i1) {
    if (i0 == 0) {
#pragma unroll
      for (int m = 0; m < 4; ++m) hac[m] = (f32x4){0.f, 0.f, 0.f, 0.f};
    }
    for (int i = i0; i < i1; ++i) {      // ks = w*4+i  (0..31 over 8 waves)
      const int ks = w * 4 + i;
      bf16x8 bfr = *(const bf16x8*)&w1s[((4 * ks + l4) * 16 + l15) * 8];
      if (USE_XBF) {
        const __bf16* xb = xbf + (size_t)tt * 65536 + (size_t)ks * 2048;
#pragma unroll
        for (int m = 0; m < 4; ++m) {
          bf16x8 af = *(const bf16x8*)&xb[(m * 64 + l) * 8];
          hac[m] = __builtin_amdgcn_mfma_f32_16x16x32_bf16(af, bfr, hac[m], 0, 0, 0);
        }
      } else {
        const int k = ks * 32 + l4 * 8;
#pragma unroll
        for (int m = 0; m < 4; ++m) {
          const int row = m * 16 + l15;
          const float* p = x + ((size_t)row * TT + tt) * ISZ + k;
          float4 f0 = *(const float4*)p;
          float4 f1 = *(const float4*)(p + 4);
          bf16x8 af;
          af[0] = (__bf16)f0.x; af[1] = (__bf16)f0.y;
          af[2] = (__bf16)f0.z; af[3] = (__bf16)f0.w;
          af[4] = (__bf16)f1.x; af[5] = (__bf16)f1.y;
          af[6] = (__bf16)f1.z; af[7] = (__bf16)f1.w;
          hac[m] = __builtin_amdgcn_mfma_f32_16x16x32_bf16(af, bfr, hac[m], 0, 0, 0);
        }
      }
    }
  };

  for (int t = 0; t < TT; ++t) {
    f32x4 hac[4];
    if (lmode) {
      // ---------- x-half part 1 (2 K-slices): covers the stage-poll wait ----------
      do_xhalf_range(t, hac, 0, 2);
      // ---------- stage hx slice kh=xrank into XCD-local copy ----------
      if (tid < 8) {                     // poll our slice's 8 producers (post-C(t-1))
        const unsigned* p = &arr[stgj * 32];
        int guard = 0;
        for (;;) {
          unsigned v = __hip_atomic_load(p, __ATOMIC_RELAXED, SCOPE_AGENT);
          if (__all(v >= tc)) break;
          if (++guard > (1 << 20)) break;  // fail-safe
          __builtin_amdgcn_s_sleep(1);
        }
      }
      asm volatile("" ::: "memory");
      __syncthreads();                   // stage readers wait for the poll
      if (tid < 256) {                   // copy 4 KB slice: master(nt) -> local(cached)
        const int off = xrank * 2048 + tid * 8;
        bf16x8 v = nt_ld16(hxbf + off);
        *(bf16x8*)(hxl + off) = v;       // normal store: dirty line in OUR L2
      }
      ++tc; xbar_arrive(xarr, xk, xrank, tc);   // syncthreads drains the stores
      // ---------- x-half part 2 (2 K-slices): covers the xbar2 wait ----------
      do_xhalf_range(t, hac, 2, 4);
      xbar_wait(xarr, xk, tc);           // full hx staged in local L2

      // ---------- Phase A, hx-half: normal loads, local L2 hits ----------
#pragma unroll
      for (int i = 0; i < 4; ++i) {      // kh = w*4 .. w*4+4
        const int kh = w * 4 + i;
        bf16x8 bfr = *(const bf16x8*)&w1s[((4 * (32 + kh) + l4) * 16 + l15) * 8];
#pragma unroll
        for (int m = 0; m < 4; ++m) {
          bf16x8 af = *(const bf16x8*)&hxl[((kh * 4 + m) * 64 + l) * 8];
          hac[m] = __builtin_amdgcn_mfma_f32_16x16x32_bf16(af, bfr, hac[m], 0, 0, 0);
        }
      }
    } else {
      // ---------- fallback: R9 path (x-half, direct poll, nt hx reads) ----------
      do_xhalf_range(t, hac, 0, 4);
      {
        const unsigned* p = &arr[prodj * 32];
        int guard = 0;
        for (;;) {
          unsigned v = __hip_atomic_load(p, __ATOMIC_RELAXED, SCOPE_AGENT);
          if (__all(v >= tc)) break;
          if (++guard > (1 << 20)) break;
          __builtin_amdgcn_s_sleep(1);
        }
        asm volatile("" ::: "memory");
      }
      ++tc;                              // keep tc aligned with lmode's xbar2 bump
#pragma unroll
      for (int i = 0; i < 4; ++i) {
        const int kh = w * 4 + i;
        bf16x8 bfr = *(const bf16x8*)&w1s[((4 * (32 + kh) + l4) * 16 + l15) * 8];
#pragma unroll
        for (int m = 0; m < 4; ++m) {
          bf16x8 af = nt_ld16(&hxbf[((kh * 4 + m) * 64 + l) * 8]);
          hac[m] = __builtin_amdgcn_mfma_f32_16x16x32_bf16(af, bfr, hac[m], 0, 0, 0);
        }
      }
    }

#pragma unroll
    for (int m = 0; m < 4; ++m)
      *(f32x4*)&red[((w * 4 + m) * 64 + l) * 4] = hac[m];
    __syncthreads();
    if (w < 4) {                         // wave w owns m-tile w: rows 16w..16w+16
      f32x4 h = *(const f32x4*)&red[((0 * 4 + w) * 64 + l) * 4];
#pragma unroll
      for (int s = 1; s < 8; ++s)
        h += *(const f32x4*)&red[((s * 4 + w) * 64 + l) * 4];
#pragma unroll
      for (int r = 0; r < 4; ++r)        // C layout: col=l15, row=16w+4*l4+r
        abuf[(w * 16 + l4 * 4 + r) * 16 + l15] = (__bf16)(h[r] + b1v);
    }
    __syncthreads();
    if (tid < 128) {                     // h-tile -> hbf master frag image (coherent)
      const int m = tid >> 5, q2s = (tid >> 4) & 1, rr = tid & 15;
      bf16x8 vv = *(const bf16x8*)&abuf[(m * 16 + rr) * 16 + q2s * 8];
      const int k2 = j >> 1, q2 = (j & 1) * 2 + q2s;
      coh_st16(&hbf[(((k2 * 4 + m) * 64) + q2 * 16 + rr) * 8], vv);
    }
    // ---------- post-A: arrive + flat 1-hop all-wave wait (no aggregator hop) ----------
    ++tc;
    gbar_arrive(arr, j, tc);
    flat_wait_all(arr, tc);              // h globally visible

    // ---------- Phase B: a = gelu(LN(h)) computed once per XCD copy ----------
    if (lmode) {
      const int u = tid;
      const int R0 = xrank * 2, R1 = R0 + 1;
      const int i0 = frag_idx(R0, u), i1 = frag_idx(R1, u);
      bf16x8 h0 = nt_ld16(hbf + i0);
      bf16x8 h1 = nt_ld16(hbf + i1);
      float s0 = 0.f, q0 = 0.f, s1 = 0.f, q1 = 0.f;
#pragma unroll
      for (int e = 0; e < 8; ++e) {
        float v0 = (float)h0[e], v1 = (float)h1[e];
        s0 += v0; q0 += v0 * v0; s1 += v1; q1 += v1 * v1;
      }
#pragma unroll
      for (int m = 1; m < 64; m <<= 1) {
        s0 += __shfl_xor(s0, m, 64); q0 += __shfl_xor(q0, m, 64);
        s1 += __shfl_xor(s1, m, 64); q1 += __shfl_xor(q1, m, 64);
      }
      if (l == 0) *(f32x4*)&red[4096 + w * 4] = (f32x4){s0, q0, s1, q1};
      __syncthreads();
      float S0 = 0.f, Q0 = 0.f, S1 = 0.f, Q1 = 0.f;
#pragma unroll
      for (int w2 = 0; w2 < 8; ++w2) {
        f32x4 p = *(const f32x4*)&red[4096 + w2 * 4];
        S0 += p[0]; Q0 += p[1]; S1 += p[2]; Q1 += p[3];
      }
      const float mu0 = S0 * (1.f / 4096.f), mu1 = S1 * (1.f / 4096.f);
      const float rs0 = rsqrtf(Q0 * (1.f / 4096.f) - mu0 * mu0 + LN_EPS);
      const float rs1 = rsqrtf(Q1 * (1.f / 4096.f) - mu1 * mu1 + LN_EPS);
      const int c0 = (u >> 2) * 32 + (u & 3) * 8;
      float4 ga = *(const float4*)(ln_g + c0), gb = *(const float4*)(ln_g + c0 + 4);
      float4 ea = *(const float4*)(ln_b + c0), eb = *(const float4*)(ln_b + c0 + 4);
      float gk[8] = {ga.x, ga.y, ga.z, ga.w, gb.x, gb.y, gb.z, gb.w};
      float ek[8] = {ea.x, ea.y, ea.z, ea.w, eb.x, eb.y, eb.z, eb.w};
      bf16x8 a0, a1;
#pragma unroll
      for (int e = 0; e < 8; ++e) {
        a0[e] = (__bf16)gelu_f(((float)h0[e] - mu0) * rs0 * gk[e] + ek[e]);
        a1[e] = (__bf16)gelu_f(((float)h1[e] - mu1) * rs1 * gk[e] + ek[e]);
      }
      *(bf16x8*)(abl + i0) = a0;         // normal cached stores: XCD-local copy
      *(bf16x8*)(abl + i1) = a1;
    } else {                             // fallback: gelu once into master abf
      const int u = tid;
      const int R = j >> 2, q = j & 3;
      const int iR = frag_idx(R, u);
      bf16x8 hv = nt_ld16(hbf + iR);
      float s0 = 0.f, q0 = 0.f;
#pragma unroll
      for (int e = 0; e < 8; ++e) { float v = (float)hv[e]; s0 += v; q0 += v * v; }
#pragma unroll
      for (int m = 1; m < 64; m <<= 1) {
        s0 += __shfl_xor(s0, m, 64); q0 += __shfl_xor(q0, m, 64);
      }
      if (l == 0) { red[4096 + w * 2] = s0; red[4096 + w * 2 + 1] = q0; }
      __syncthreads();
      float S = 0.f, Q = 0.f;
#pragma unroll
      for (int w2 = 0; w2 < 8; ++w2) { S += red[4096 + w2 * 2]; Q += red[4096 + w2 * 2 + 1]; }
      const float mu = S * (1.f / 4096.f);
      const float rs = rsqrtf(Q * (1.f / 4096.f) - mu * mu + LN_EPS);
      if ((tid >> 7) == q) {
        const int c0 = (u >> 2) * 32 + (u & 3) * 8;
        float4 ga = *(const float4*)(ln_g + c0), gb = *(const float4*)(ln_g + c0 + 4);
        float4 ea = *(const float4*)(ln_b + c0), eb = *(const float4*)(ln_b + c0 + 4);
        float gk[8] = {ga.x, ga.y, ga.z, ga.w, gb.x, gb.y, gb.z, gb.w};
        float ek[8] = {ea.x, ea.y, ea.z, ea.w, eb.x, eb.y, eb.z, eb.w};
        bf16x8 av;
#pragma unroll
        for (int e = 0; e < 8; ++e)
          av[e] = (__bf16)gelu_f(((float)hv[e] - mu) * rs * gk[e] + ek[e]);
        coh_st16(abf + iR, av);
      }
    }

    // ---------- B->C sync: arrive, w2p prefetch in gap, 8-producer subset poll ----------
    ++tc;
    if (lmode) xbar_arrive(xarr, xk, xrank, tc);
    else       gbar_arrive(arr, j, tc);
    bf16x8 wreg[16];
#pragma unroll
    for (int i = 0; i < 16; ++i)
      wreg[i] = *(const bf16x8*)&w2p[((size_t)cg * 512 + (w * 16 + i) * 4 + l4) * 128 + l15 * 8];
    if (lmode) {
      // C reads abl rows [16g,16g+16) = produced by same-XCD xrank in [8g,8g+8)
      if (tid < 8) {
        const unsigned* p = &xarr[(xk * 32 + 8 * g + tid) * 32];
        int guard = 0;
        for (;;) {
          unsigned v = __hip_atomic_load(p, __ATOMIC_RELAXED, SCOPE_AGENT);
          if (__all(v >= tc)) break;
          if (++guard > (1 << 20)) break;  // fail-safe
          __builtin_amdgcn_s_sleep(1);
        }
      }
      asm volatile("" ::: "memory");
      __syncthreads();
    } else {
      gbar_wait(arr, gflag, j, tc);
    }

    // ---------- Phase C: hx_new[16g.., 16cg..] = a @ W2 + b2 + hx (pure MFMA) ----------
    {
      f32x4 cac = {0.f, 0.f, 0.f, 0.f};
      if (lmode) {
#pragma unroll
        for (int i = 0; i < 16; ++i) {
          const int s2 = w * 16 + i;
          bf16x8 af = *(const bf16x8*)&abl[((s2 * 4 + g) * 64 + l) * 8];  // local L2
          cac = __builtin_amdgcn_mfma_f32_16x16x32_bf16(af, wreg[i], cac, 0, 0, 0);
        }
      } else {
#pragma unroll
        for (int i = 0; i < 16; ++i) {
          const int s2 = w * 16 + i;
          bf16x8 af = nt_ld16(&abf[((s2 * 4 + g) * 64 + l) * 8]);
          cac = __builtin_amdgcn_mfma_f32_16x16x32_bf16(af, wreg[i], cac, 0, 0, 0);
        }
      }
      *(f32x4*)&red[(w * 64 + l) * 4] = cac;
    }
    __syncthreads();
    if (w < 4) {                         // parallel epilogue: wave w handles r=w
      float s = 0.f;
#pragma unroll
      for (int w2 = 0; w2 < 8; ++w2) s += red[(w2 * 64 + l) * 4 + w];
      const int row = g * 16 + l4 * 4 + w;
      const int c = cg * 16 + l15;
      const float vNew = s + b2v + hxf32[row * ISZ + c];   // private, cached
      hxf32[row * ISZ + c] = vNew;
      out[((size_t)row * TT + t) * ISZ + c] = vNew;        // write-once, cached
      const int kh = c >> 5, lh = ((c >> 3) & 3) * 16 + (row & 15), mh = row >> 4;
      union { __bf16 b; unsigned short s16; } cv; cv.b = (__bf16)vNew;
      __hip_atomic_store((unsigned short*)&hxbf[((kh * 4 + mh) * 64 + lh) * 8 + (c & 7)],
                         cv.s16, __ATOMIC_RELAXED, SCOPE_AGENT);
    }
    ++tc; gbar_arrive(arr, j, tc);       // post-C arrive; stagers poll our arr line
  }
}

// ---------------- host ----------------
extern "C" void kernel_launch(void* const* d_in, const int* in_sizes, int n_in,
                              void* d_out, int out_size, void* d_ws, size_t ws_size,
                              hipStream_t stream) {
  const float* x       = (const float*)d_in[0];
  const float* W1      = (const float*)d_in[1];
  const float* b1      = (const float*)d_in[2];
  const float* ln_g    = (const float*)d_in[3];
  const float* ln_b    = (const float*)d_in[4];
  const float* W2      = (const float*)d_in[5];
  const float* b2      = (const float*)d_in[6];
  const float* init_hx = (const float*)d_in[7];
  float* out = (float*)d_out;

  char* ws = (char*)d_ws;
  __bf16* w1p     = (__bf16*)(ws);                       // 16 MB @ 0
  __bf16* w2p     = (__bf16*)(ws + 16777216ull);         // 8 MB
  __bf16* hbf     = (__bf16*)(ws + 25165824ull);         // 512 KB master h
  __bf16* abf     = (__bf16*)(ws + 25690112ull);         // 512 KB master a (fallback)
  __bf16* ablocal = (__bf16*)(ws + 26214400ull);         // 8 x 512 KB per-XCD a copies
  __bf16* hxbf    = (__bf16*)(ws + 30408704ull);         // 128 KB master hx
  float* hxf32    = (float*)(ws + 30539776ull);          // 256 KB
  unsigned* arr   = (unsigned*)(ws + 30801920ull);       // 32 KB arrival flags
  unsigned* gflag = (unsigned*)(ws + 30834688ull);       // 1 KB group flags
  unsigned* xarr  = (unsigned*)(ws + 30835712ull);       // 32 KB XCD-barrier flags
  unsigned* ticket= (unsigned*)(ws + 30868480ull);       // 128 B tickets
  __bf16* hxlocal = (__bf16*)(ws + 31457280ull);         // 8 x 128 KB per-XCD hx copies @ 30 MB
  __bf16* xbf     = (__bf16*)(ws + 33554432ull);         // 64 MB @ 32 MB
  const bool use_xbf = (ws_size >= 33554432ull + 67108864ull);

  prep_w1<<<4096, 256, 0, stream>>>(W1, w1p);
  prep_w2<<<2048, 256, 0, stream>>>(W2, w2p);
  prep_state<<<256, 256, 0, stream>>>(init_hx, hxf32, hxbf, arr);
  if (use_xbf) {
    prep_x<<<16384, 256, 0, stream>>>(x, xbf);
    rnn_persist<true><<<NBLK, NTHR, 0, stream>>>(
        x, b1, ln_g, ln_b, b2, out, w1p, w2p, xbf, hbf, abf, ablocal,
        hxlocal, hxbf, hxf32, arr, gflag, xarr, ticket);
  } else {
    rnn_persist<false><<<NBLK, NTHR, 0, stream>>>(
        x, b1, ln_g, ln_b, b2, out, w1p, w2p, xbf, hbf, abf, ablocal,
        hxlocal, hxbf, hxf32, arr, gflag, xarr, ticket);
  }
}